// Round 2
// baseline (11.872 us; speedup 1.0000x reference)
//
#include <hip/hip_runtime.h>
#include <math.h>

// x: [B=4, C=3, H=256, W=256] f32; REGION=3, h=0.5 -> logits = -2*d2
// out[b,i,j] = log(9) + 3*log(sqrt(2pi)*0.5) - (1/9) * sum_n log( sum_m exp(-2*d2[n][m]) )

#define TX 64
#define TY 4
#define HH 256
#define WW 256
#define HP 254
#define WP 254

__global__ __launch_bounds__(256) void je_kernel(const float* __restrict__ x,
                                                 float* __restrict__ out) {
    __shared__ float lds[3][TY + 2][TX + 2];

    const int b   = blockIdx.z;
    const int by  = blockIdx.y;   // 0..63  (rows)
    const int bx  = blockIdx.x;   // 0..3   (cols)
    const int tid = threadIdx.x;

    const int row0 = by * TY;
    const int col0 = bx * TX;

    const float* xb = x + (size_t)b * 3 * HH * WW;

    // Stage 3*(TY+2)*(TX+2) = 1188 floats, coalesced.
    constexpr int NE = 3 * (TY + 2) * (TX + 2);
    for (int e = tid; e < NE; e += 256) {
        int c    = e / ((TY + 2) * (TX + 2));
        int rem  = e - c * ((TY + 2) * (TX + 2));
        int r    = rem / (TX + 2);
        int col  = rem - r * (TX + 2);
        int grow = row0 + r, gcol = col0 + col;
        float v = 0.0f;
        if (grow < HH && gcol < WW)
            v = xb[(size_t)c * HH * WW + (size_t)grow * WW + gcol];
        lds[c][r][col] = v;
    }
    __syncthreads();

    const int tx = tid & (TX - 1);
    const int ty = tid >> 6;
    const int i = row0 + ty, j = col0 + tx;
    if (i >= HP || j >= WP) return;

    // Gather 3x3x3 patch from LDS (stride-1 across lanes -> conflict-free)
    float p[9][3];
#pragma unroll
    for (int c = 0; c < 3; ++c)
#pragma unroll
        for (int di = 0; di < 3; ++di)
#pragma unroll
            for (int dj = 0; dj < 3; ++dj)
                p[di * 3 + dj][c] = lds[c][ty + di][tx + dj];

    float s[9];
#pragma unroll
    for (int n = 0; n < 9; ++n) s[n] = 1.0f;

    // exp(-2*dd) = exp2(dd * -2*log2(e))
    const float K = -2.8853900818f;
#pragma unroll
    for (int n = 0; n < 9; ++n) {
#pragma unroll
        for (int m = n + 1; m < 9; ++m) {
            float d0 = p[n][0] - p[m][0];
            float d1 = p[n][1] - p[m][1];
            float d2 = p[n][2] - p[m][2];
            float dd = fmaf(d0, d0, fmaf(d1, d1, d2 * d2));
            float e = exp2f(dd * K);
            s[n] += e;
            s[m] += e;
        }
    }

    float acc = 0.0f;
#pragma unroll
    for (int n = 0; n < 9; ++n) acc += __log2f(s[n]);

    // log(9) + 3*log(sqrt(2*pi)*0.5);  acc*ln2/9
    const float cst = 2.8745986353f;
    out[(size_t)b * HP * WP + (size_t)i * WP + j] = cst - acc * (0.69314718056f / 9.0f);
}

extern "C" void kernel_launch(void* const* d_in, const int* in_sizes, int n_in,
                              void* d_out, int out_size, void* d_ws, size_t ws_size,
                              hipStream_t stream) {
    const float* x = (const float*)d_in[0];
    float* out = (float*)d_out;

    dim3 grid((WP + TX - 1) / TX, (HP + TY - 1) / TY, 4);  // 4 x 64 x 4
    je_kernel<<<grid, 256, 0, stream>>>(x, out);
}

// Round 3
// 10.487 us; speedup vs baseline: 1.1320x; 1.1320x over previous
//
#include <hip/hip_runtime.h>
#include <math.h>

// x: [B=4, C=3, H=256, W=256] f32; REGION=3, h=0.5 -> logits = -2*d2
// out[b,i,j] = log(9) + 3*log(sqrt(2pi)*0.5) - (1/9) * sum_n log( sum_m exp(-2*d2[n][m]) )
// Each thread computes 4 consecutive output pixels from a shared 3x6x3 point set;
// the 45 pair-distances shared between adjacent windows are CSE'd by the compiler.

#define HP 254
#define WP 254

__global__ __launch_bounds__(256) void je_kernel(const float* __restrict__ x,
                                                 float* __restrict__ out) {
    int t = blockIdx.x * 256 + threadIdx.x;          // 254 blocks * 256 = 65024 = 4*254*64
    const int g = t & 63;                            // col group: pixels j0..j0+3
    int rest = t >> 6;
    const int i = rest % HP;
    const int b = rest / HP;                         // 0..3
    const int j0 = g << 2;

    const float* xb = x + (size_t)b * 3 * 65536;

    // Point set: 3 rows x 6 cols x 3 chans
    float p[3][6][3];
#pragma unroll
    for (int c = 0; c < 3; ++c) {
#pragma unroll
        for (int r = 0; r < 3; ++r) {
            const float* rowp = xb + c * 65536 + (i + r) * 256 + j0;
            float4 v = *(const float4*)rowp;          // 16B aligned: j0 % 4 == 0
            p[r][0][c] = v.x; p[r][1][c] = v.y; p[r][2][c] = v.z; p[r][3][c] = v.w;
            if (g < 63) {
                float2 w = *(const float2*)(rowp + 4);
                p[r][4][c] = w.x; p[r][5][c] = w.y;
            } else {                                  // cols 256,257 OOB; only pixels k<2 valid
                p[r][4][c] = 0.0f; p[r][5][c] = 0.0f;
            }
        }
    }

    float s[4][9];
#pragma unroll
    for (int k = 0; k < 4; ++k)
#pragma unroll
        for (int n = 0; n < 9; ++n) s[k][n] = 1.0f;

    const float K = -2.8853900818f;                   // -2*log2(e)
#pragma unroll
    for (int k = 0; k < 4; ++k) {
#pragma unroll
        for (int n = 0; n < 9; ++n) {
            const int r1 = n / 3, c1 = k + n % 3;
#pragma unroll
            for (int m = n + 1; m < 9; ++m) {
                const int r2 = m / 3, c2 = k + m % 3;
                float d0 = p[r1][c1][0] - p[r2][c2][0];
                float d1 = p[r1][c1][1] - p[r2][c2][1];
                float d2 = p[r1][c1][2] - p[r2][c2][2];
                float dd = fmaf(d0, d0, fmaf(d1, d1, d2 * d2));
                float e = exp2f(dd * K);              // shared pairs CSE across k
                s[k][n] += e;
                s[k][m] += e;
            }
        }
    }

    const float cst = 2.8745986353f;                  // log(9) + 3*log(sqrt(2pi)*0.5)
    float r0[4];
#pragma unroll
    for (int k = 0; k < 4; ++k) {
        float acc = 0.0f;
#pragma unroll
        for (int n = 0; n < 9; ++n) acc += __log2f(s[k][n]);
        r0[k] = cst - acc * (0.69314718056f / 9.0f);
    }

    float* op = out + (size_t)b * HP * WP + (size_t)i * WP + j0;
    if (g < 63) {
        *(float2*)op       = make_float2(r0[0], r0[1]);   // 8B aligned (even offsets)
        *(float2*)(op + 2) = make_float2(r0[2], r0[3]);
    } else {
        op[0] = r0[0];
        op[1] = r0[1];
    }
}

extern "C" void kernel_launch(void* const* d_in, const int* in_sizes, int n_in,
                              void* d_out, int out_size, void* d_ws, size_t ws_size,
                              hipStream_t stream) {
    const float* x = (const float*)d_in[0];
    float* out = (float*)d_out;
    je_kernel<<<254, 256, 0, stream>>>(x, out);
}